// Round 7
// baseline (448.416 us; speedup 1.0000x reference)
//
#include <hip/hip_runtime.h>

// CompressiveMemory.update() — B=65536, R=K=8, D=256, fp32.
//   k0 transpose_pack: W (o,i,k) -> Wt2[m4][o][j] (m=i*2+k), 512KB in ws.
//   k1 fused_update: grid=8192, G=8 samples/block. Streaming pair-loop
//      (8 nt-loads in flight, scalar prefetch of next pair's cnt/valid);
//      shift samples stage x=[cm7,fm0] into LDS slot j. At block end, ONE
//      batched multi-conv pass over Wt2 computes all <=8 convs (W read once).

#define NB 65536
#define RR 8
#define KK 8
#define DD 256
#define WFLOATS (DD * DD * 2)
#define G 8                      // samples per block; grid = NB/G

typedef float f4 __attribute__((ext_vector_type(4)));

static __device__ __forceinline__ f4 ntload(const float* p) {
    return __builtin_nontemporal_load((const f4*)p);
}
static __device__ __forceinline__ void ntstore(float* p, f4 v) {
    __builtin_nontemporal_store(v, (f4*)p);
}

__global__ __launch_bounds__(256) void transpose_pack(
    const float* __restrict__ W, float* __restrict__ Wt2)
{
    int t = blockIdx.x * 256 + threadIdx.x;   // coalesced read of W
    int o = t >> 9;
    int m = t & 511;                          // m = i*2 + k
    Wt2[(size_t)(m >> 2) * (DD * 4) + o * 4 + (m & 3)] = W[t];
}

__global__ __launch_bounds__(256) void fused_update(
    const float* __restrict__ fm,          // (B,R,D)
    const float* __restrict__ cm,          // (B,K,D)
    const int* __restrict__ cnt_in,
    const float* __restrict__ seg,         // (B,D)
    const int* __restrict__ valid,
    const float* __restrict__ Wt2,         // (128, 256, 4)
    const float* __restrict__ bias,        // (256,)
    float* __restrict__ out_fm,
    float* __restrict__ out_cm,
    float* __restrict__ out_cnt)
{
    __shared__ float xbuf[G][512];         // 16KB; slot j = sample base+j

    const int tid  = threadIdx.x;
    const int w    = tid >> 6;             // 0..3
    const int lane = tid & 63;
    const int c    = lane << 2;
    const int base = blockIdx.x * G;

    const int r0 = w, r1 = w + 4;
    int mask = 0;                          // block-uniform shift mask

    // scalar prefetch of first pair
    int nxt_cA = cnt_in[base + 0], nxt_cB = cnt_in[base + 1];
    int nxt_vA = valid[base + 0],  nxt_vB = valid[base + 1];

    for (int j = 0; j < G; j += 2) {
        const int bA = base + j, bB = base + j + 1;
        const int cntA = nxt_cA, cntB = nxt_cB;
        const bool vA = nxt_vA != 0, vB = nxt_vB != 0;
        if (j + 2 < G) {                    // prefetch next pair
            nxt_cA = cnt_in[bA + 2]; nxt_cB = cnt_in[bB + 2];
            nxt_vA = valid[bA + 2];  nxt_vB = valid[bB + 2];
        }

        const bool insA = vA && (cntA < RR), shfA = vA && (cntA >= RR);
        const bool insB = vB && (cntB < RR), shfB = vB && (cntB >= RR);

        const float* fmA  = fm  + (size_t)bA * (RR * DD);
        const float* cmA  = cm  + (size_t)bA * (KK * DD);
        const float* segA = seg + (size_t)bA * DD;
        const float* fmB  = fm  + (size_t)bB * (RR * DD);
        const float* cmB  = cm  + (size_t)bB * (KK * DD);
        const float* segB = seg + (size_t)bB * DD;
        float* ofmA = out_fm + (size_t)bA * (RR * DD);
        float* ocmA = out_cm + (size_t)bA * (KK * DD);
        float* ofmB = out_fm + (size_t)bB * (RR * DD);
        float* ocmB = out_cm + (size_t)bB * (KK * DD);

        // source selection (wave-uniform)
        const float* f0A = shfA ? fmA + (r0 + 1) * DD
                                : (insA && r0 == cntA) ? segA : fmA + r0 * DD;
        const float* f1A = shfA ? ((r1 < 7) ? fmA + (r1 + 1) * DD : segA)
                                : (insA && r1 == cntA) ? segA : fmA + r1 * DD;
        const bool   c1A = !(shfA && r1 == 7);
        const float* c0A = cmA + (shfA ? r0 + 1 : r0) * DD;
        const float* c1Ap = c1A ? cmA + (shfA ? r1 + 1 : r1) * DD : cmA;

        const float* f0B = shfB ? fmB + (r0 + 1) * DD
                                : (insB && r0 == cntB) ? segB : fmB + r0 * DD;
        const float* f1B = shfB ? ((r1 < 7) ? fmB + (r1 + 1) * DD : segB)
                                : (insB && r1 == cntB) ? segB : fmB + r1 * DD;
        const bool   c1B = !(shfB && r1 == 7);
        const float* c0B = cmB + (shfB ? r0 + 1 : r0) * DD;
        const float* c1Bp = c1B ? cmB + (shfB ? r1 + 1 : r1) * DD : cmB;

        // issue all 8 stream loads (MLP=8 per wave)
        f4 a0 = ntload(f0A + c);
        f4 a1 = ntload(f1A + c);
        f4 a2 = ntload(c0A + c);
        f4 a3 = ntload(c1Ap + c);
        f4 b0 = ntload(f0B + c);
        f4 b1 = ntload(f1B + c);
        f4 b2 = ntload(c0B + c);
        f4 b3 = ntload(c1Bp + c);

        ntstore(ofmA + r0 * DD + c, a0);
        ntstore(ofmA + r1 * DD + c, a1);
        ntstore(ocmA + r0 * DD + c, a2);
        if (c1A) ntstore(ocmA + r1 * DD + c, a3);
        ntstore(ofmB + r0 * DD + c, b0);
        ntstore(ofmB + r1 * DD + c, b1);
        ntstore(ocmB + r0 * DD + c, b2);
        if (c1B) ntstore(ocmB + r1 * DD + c, b3);

        if (tid == 0) {
            out_cnt[bA] = (float)(cntA + (insA ? 1 : 0));
            out_cnt[bB] = (float)(cntB + (insB ? 1 : 0));
        }

        // stage conv inputs (LDS dynamic slot j is fine; no conv here)
        if (shfA) {
            xbuf[j][tid * 2]     = cmA[(KK - 1) * DD + tid];
            xbuf[j][tid * 2 + 1] = fmA[tid];
            mask |= 1 << j;
        }
        if (shfB) {
            xbuf[j + 1][tid * 2]     = cmB[(KK - 1) * DD + tid];
            xbuf[j + 1][tid * 2 + 1] = fmB[tid];
            mask |= 2 << j;
        }
    }

    if (mask) {
        __syncthreads();                   // xbuf visible block-wide
        float acc[G];
        #pragma unroll
        for (int s = 0; s < G; ++s) acc[s] = 0.f;

        const float* wp = Wt2 + tid * 4;
        for (int m4 = 0; m4 < 128; ++m4) {
            const f4 wq = *(const f4*)(wp + (size_t)m4 * (DD * 4)); // 4KB coalesced, L2-hot
            #pragma unroll
            for (int s = 0; s < G; ++s) {  // unused slots compute garbage (harmless)
                const f4 xq = *(const f4*)&xbuf[s][m4 * 4];         // uniform broadcast
                acc[s] += xq.x * wq.x + xq.y * wq.y + xq.z * wq.z + xq.w * wq.w;
            }
        }
        const float bv = bias[tid];
        #pragma unroll
        for (int s = 0; s < G; ++s)
            if ((mask >> s) & 1)
                out_cm[((size_t)(base + s) * KK + (KK - 1)) * DD + tid] = acc[s] + bv;
    }
}

extern "C" void kernel_launch(void* const* d_in, const int* in_sizes, int n_in,
                              void* d_out, int out_size, void* d_ws, size_t ws_size,
                              hipStream_t stream) {
    const float* fm    = (const float*)d_in[0];
    const float* cm    = (const float*)d_in[1];
    const int*   cnt   = (const int*)d_in[2];
    const float* seg   = (const float*)d_in[3];
    const int*   valid = (const int*)d_in[4];
    const float* W     = (const float*)d_in[5];
    const float* bias  = (const float*)d_in[6];

    float* out_fm  = (float*)d_out;
    float* out_cm  = out_fm + (size_t)NB * RR * DD;
    float* out_cnt = out_cm + (size_t)NB * KK * DD;

    float* Wt2 = (float*)d_ws;             // 512KB

    hipLaunchKernelGGL(transpose_pack, dim3(WFLOATS / 256), dim3(256), 0, stream, W, Wt2);
    hipLaunchKernelGGL(fused_update, dim3(NB / G), dim3(256), 0, stream,
                       fm, cm, cnt, seg, valid, Wt2, bias, out_fm, out_cm, out_cnt);
}

// Round 8
// 422.079 us; speedup vs baseline: 1.0624x; 1.0624x over previous
//
#include <hip/hip_runtime.h>

// CompressiveMemory.update() — B=65536, R=K=8, D=256, fp32.
// R5 structure (best: 417.4us): 1 block/sample, fused inline conv.
// R8 change: stream LOADS are plain cached (match m13 copy-ubench policy);
// STORES stay nontemporal (write-once, keep L2 clean for Wt2 residency).
//   k0 transpose_pack: W (o,i,k) -> Wt2[m4][o][j] (m=i*2+k), 512KB in ws.
//   k1 fused_update: 1 block (256 thr) per sample; wave w copies fm rows
//      {w,w+4}, cm rows {w,w+4} (MLP=4); shift blocks run 2-tap conv inline
//      (block-uniform branch), x staged in LDS, coalesced Wt2 reads (L2-hot).

#define NB 65536
#define RR 8
#define KK 8
#define DD 256
#define WFLOATS (DD * DD * 2)

typedef float f4 __attribute__((ext_vector_type(4)));

static __device__ __forceinline__ void ntstore(float* p, f4 v) {
    __builtin_nontemporal_store(v, (f4*)p);
}

__global__ __launch_bounds__(256) void transpose_pack(
    const float* __restrict__ W, float* __restrict__ Wt2)
{
    int t = blockIdx.x * 256 + threadIdx.x;   // coalesced read of W
    int o = t >> 9;
    int m = t & 511;                          // m = i*2 + k
    Wt2[(size_t)(m >> 2) * (DD * 4) + o * 4 + (m & 3)] = W[t];
}

__global__ __launch_bounds__(256) void fused_update(
    const float* __restrict__ fm,          // (B,R,D)
    const float* __restrict__ cm,          // (B,K,D)
    const int* __restrict__ cnt_in,
    const float* __restrict__ seg,         // (B,D)
    const int* __restrict__ valid,
    const float* __restrict__ Wt2,         // (128, 256, 4)
    const float* __restrict__ bias,        // (256,)
    float* __restrict__ out_fm,
    float* __restrict__ out_cm,
    float* __restrict__ out_cnt)
{
    __shared__ float xbuf[512];            // x[2i]=cm7[i], x[2i+1]=fm0[i]

    const int b    = blockIdx.x;
    const int tid  = threadIdx.x;
    const int w    = tid >> 6;             // 0..3
    const int lane = tid & 63;
    const int c    = lane << 2;

    const int  cnt = cnt_in[b];
    const bool v   = valid[b] != 0;
    const bool ins = v && (cnt < RR);
    const bool shf = v && (cnt >= RR);     // block-uniform

    const float* fmb  = fm  + (size_t)b * (RR * DD);
    const float* cmb  = cm  + (size_t)b * (KK * DD);
    const float* segb = seg + (size_t)b * DD;
    float* ofm = out_fm + (size_t)b * (RR * DD);
    float* ocm = out_cm + (size_t)b * (KK * DD);

    const int r0 = w, r1 = w + 4;

    // fm sources (wave-uniform selection)
    const float* f0src = shf ? fmb + (r0 + 1) * DD
                             : (ins && r0 == cnt) ? segb : fmb + r0 * DD;
    const float* f1src = shf ? ((r1 < 7) ? fmb + (r1 + 1) * DD : segb)
                             : (ins && r1 == cnt) ? segb : fmb + r1 * DD;
    // cm sources; shf && row==7 produced by inline conv below
    const bool   c1st  = !(shf && r1 == 7);
    const float* c0src = cmb + (shf ? r0 + 1 : r0) * DD;
    const float* c1src = c1st ? cmb + (shf ? r1 + 1 : r1) * DD : cmb;

    // issue all stream loads first (MLP=4) — plain cached loads
    f4 a  = *(const f4*)(f0src + c);
    f4 bq = *(const f4*)(f1src + c);
    f4 d  = *(const f4*)(c0src + c);
    f4 e  = *(const f4*)(c1src + c);

    ntstore(ofm + r0 * DD + c, a);
    ntstore(ofm + r1 * DD + c, bq);
    ntstore(ocm + r0 * DD + c, d);
    if (c1st) ntstore(ocm + r1 * DD + c, e);

    if (tid == 0)
        out_cnt[b] = (float)(cnt + (ins ? 1 : 0));

    if (shf) {                              // block-uniform -> barrier is safe
        // stage x interleaved: xbuf[2t]=cm7[t], xbuf[2t+1]=fm0[t]
        const float cv = cmb[(KK - 1) * DD + tid];
        const float fv = fmb[tid];
        xbuf[tid * 2]     = cv;
        xbuf[tid * 2 + 1] = fv;
        __syncthreads();

        // c_new[o] = sum_m x[m] * Wt2[m>>2][o][m&3], o = tid
        float acc = 0.f;
        const float* wp = Wt2 + tid * 4;
        #pragma unroll 8
        for (int m4 = 0; m4 < 128; ++m4) {
            const f4 wq = *(const f4*)(wp + (size_t)m4 * (DD * 4));
            const f4 xq = *(const f4*)&xbuf[m4 * 4];   // uniform -> broadcast
            acc += xq.x * wq.x + xq.y * wq.y + xq.z * wq.z + xq.w * wq.w;
        }
        acc += bias[tid];
        ocm[(KK - 1) * DD + tid] = acc;     // 1KB coalesced block store
    }
}

extern "C" void kernel_launch(void* const* d_in, const int* in_sizes, int n_in,
                              void* d_out, int out_size, void* d_ws, size_t ws_size,
                              hipStream_t stream) {
    const float* fm    = (const float*)d_in[0];
    const float* cm    = (const float*)d_in[1];
    const int*   cnt   = (const int*)d_in[2];
    const float* seg   = (const float*)d_in[3];
    const int*   valid = (const int*)d_in[4];
    const float* W     = (const float*)d_in[5];
    const float* bias  = (const float*)d_in[6];

    float* out_fm  = (float*)d_out;
    float* out_cm  = out_fm + (size_t)NB * RR * DD;
    float* out_cnt = out_cm + (size_t)NB * KK * DD;

    float* Wt2 = (float*)d_ws;             // 512KB

    hipLaunchKernelGGL(transpose_pack, dim3(WFLOATS / 256), dim3(256), 0, stream, W, Wt2);
    hipLaunchKernelGGL(fused_update, dim3(NB), dim3(256), 0, stream,
                       fm, cm, cnt, seg, valid, Wt2, bias, out_fm, out_cm, out_cnt);
}

// Round 9
// 388.944 us; speedup vs baseline: 1.1529x; 1.0852x over previous
//
#include <hip/hip_runtime.h>
#include <hip/hip_bf16.h>

// CompressiveMemory.update() — B=65536, R=K=8, D=256, fp32.
// R5 stream structure (best: 417.4us) + R9 conv changes:
//   - Wt2 stored as bf16 (halves conv L2 traffic: 512KB->256KB per conv block)
//   - per-wave conv (each wave owns 64 output channels, stages x in its own
//     LDS slice) -> no __syncthreads, no cross-wave dependency.
//   k0 transpose_pack: W (o,i,k) fp32 -> Wt2b[m4][o][j] bf16 (m=i*2+k), 256KB ws.
//   k1 fused_update: 1 block/sample; wave w copies fm rows {w,w+4}, cm rows
//      {w,w+4} (nt loads+stores, MLP=4); shift blocks run conv inline.

#define NB 65536
#define RR 8
#define KK 8
#define DD 256
#define WFLOATS (DD * DD * 2)

typedef float f4 __attribute__((ext_vector_type(4)));

static __device__ __forceinline__ f4 ntload(const float* p) {
    return __builtin_nontemporal_load((const f4*)p);
}
static __device__ __forceinline__ void ntstore(float* p, f4 v) {
    __builtin_nontemporal_store(v, (f4*)p);
}
static __device__ __forceinline__ float bf2f(unsigned short u) {
    return __uint_as_float(((unsigned int)u) << 16);
}

__global__ __launch_bounds__(256) void transpose_pack(
    const float* __restrict__ W, unsigned short* __restrict__ Wt2b)
{
    int t = blockIdx.x * 256 + threadIdx.x;   // coalesced read of W
    int o = t >> 9;
    int m = t & 511;                          // m = i*2 + k
    // round-to-nearest bf16
    __hip_bfloat16 h = __float2bfloat16(W[t]);
    Wt2b[(size_t)(m >> 2) * (DD * 4) + o * 4 + (m & 3)] = *(unsigned short*)&h;
}

__global__ __launch_bounds__(256) void fused_update(
    const float* __restrict__ fm,          // (B,R,D)
    const float* __restrict__ cm,          // (B,K,D)
    const int* __restrict__ cnt_in,
    const float* __restrict__ seg,         // (B,D)
    const int* __restrict__ valid,
    const unsigned short* __restrict__ Wt2b, // (128, 256, 4) bf16
    const float* __restrict__ bias,        // (256,)
    float* __restrict__ out_fm,
    float* __restrict__ out_cm,
    float* __restrict__ out_cnt)
{
    __shared__ float xbuf[4][512];         // per-wave slice: x[2i]=cm7[i], x[2i+1]=fm0[i]

    const int b    = blockIdx.x;
    const int tid  = threadIdx.x;
    const int w    = tid >> 6;             // 0..3
    const int lane = tid & 63;
    const int c    = lane << 2;

    const int  cnt = cnt_in[b];
    const bool v   = valid[b] != 0;
    const bool ins = v && (cnt < RR);
    const bool shf = v && (cnt >= RR);     // block-uniform

    const float* fmb  = fm  + (size_t)b * (RR * DD);
    const float* cmb  = cm  + (size_t)b * (KK * DD);
    const float* segb = seg + (size_t)b * DD;
    float* ofm = out_fm + (size_t)b * (RR * DD);
    float* ocm = out_cm + (size_t)b * (KK * DD);

    const int r0 = w, r1 = w + 4;

    // fm sources (wave-uniform selection)
    const float* f0src = shf ? fmb + (r0 + 1) * DD
                             : (ins && r0 == cnt) ? segb : fmb + r0 * DD;
    const float* f1src = shf ? ((r1 < 7) ? fmb + (r1 + 1) * DD : segb)
                             : (ins && r1 == cnt) ? segb : fmb + r1 * DD;
    // cm sources; shf && row==7 produced by inline conv below
    const bool   c1st  = !(shf && r1 == 7);
    const float* c0src = cmb + (shf ? r0 + 1 : r0) * DD;
    const float* c1src = c1st ? cmb + (shf ? r1 + 1 : r1) * DD : cmb;

    // issue all stream loads first (MLP=4) — nontemporal (R8 A/B: nt >= cached)
    f4 a  = ntload(f0src + c);
    f4 bq = ntload(f1src + c);
    f4 d  = ntload(c0src + c);
    f4 e  = ntload(c1src + c);

    ntstore(ofm + r0 * DD + c, a);
    ntstore(ofm + r1 * DD + c, bq);
    ntstore(ocm + r0 * DD + c, d);
    if (c1st) ntstore(ocm + r1 * DD + c, e);

    if (tid == 0)
        out_cnt[b] = (float)(cnt + (ins ? 1 : 0));

    if (shf) {                              // block-uniform; conv is per-wave
        // each wave stages the FULL x into its own LDS slice (no barrier)
        f4 cv = *(const f4*)(cmb + (KK - 1) * DD + c);   // cached (tiny, reread)
        f4 fv = *(const f4*)(fmb + c);
        f4 x0 = {cv.x, fv.x, cv.y, fv.y};
        f4 x1 = {cv.z, fv.z, cv.w, fv.w};
        *(f4*)&xbuf[w][2 * c]     = x0;
        *(f4*)&xbuf[w][2 * c + 4] = x1;
        // wave-internal LDS dep -> compiler emits lgkmcnt wait; no __syncthreads

        // wave w computes output channels o = 64w + lane
        const int o = (w << 6) + lane;
        float acc = 0.f;
        const unsigned short* wp = Wt2b + o * 4;
        #pragma unroll 8
        for (int m4 = 0; m4 < 128; ++m4) {
            const ushort4 wq = *(const ushort4*)(wp + (size_t)m4 * (DD * 4)); // 512B/wave, L2-hot
            const f4 xq = *(const f4*)&xbuf[w][m4 * 4];                       // uniform -> broadcast
            acc += xq.x * bf2f(wq.x) + xq.y * bf2f(wq.y)
                 + xq.z * bf2f(wq.z) + xq.w * bf2f(wq.w);
        }
        acc += bias[o];
        ocm[(KK - 1) * DD + o] = acc;       // 256B/wave coalesced
    }
}

extern "C" void kernel_launch(void* const* d_in, const int* in_sizes, int n_in,
                              void* d_out, int out_size, void* d_ws, size_t ws_size,
                              hipStream_t stream) {
    const float* fm    = (const float*)d_in[0];
    const float* cm    = (const float*)d_in[1];
    const int*   cnt   = (const int*)d_in[2];
    const float* seg   = (const float*)d_in[3];
    const int*   valid = (const int*)d_in[4];
    const float* W     = (const float*)d_in[5];
    const float* bias  = (const float*)d_in[6];

    float* out_fm  = (float*)d_out;
    float* out_cm  = out_fm + (size_t)NB * RR * DD;
    float* out_cnt = out_cm + (size_t)NB * KK * DD;

    unsigned short* Wt2b = (unsigned short*)d_ws;   // 256KB

    hipLaunchKernelGGL(transpose_pack, dim3(WFLOATS / 256), dim3(256), 0, stream, W, Wt2b);
    hipLaunchKernelGGL(fused_update, dim3(NB), dim3(256), 0, stream,
                       fm, cm, cnt, seg, valid, Wt2b, bias, out_fm, out_cm, out_cnt);
}